// Round 1
// baseline (201.965 us; speedup 1.0000x reference)
//
#include <hip/hip_runtime.h>
#include <math.h>

#define N_IMG 16
#define CCH   64
#define H     256
#define W     256
#define HW    (H*W)      // 65536
#define HW4   (HW/4)     // 16384
#define TS    16

// ---------------- Kernel 1: gray = mean over channels ----------------
__global__ __launch_bounds__(256) void gray_kernel(const float4* __restrict__ x,
                                                   float4* __restrict__ gray) {
    int bid = blockIdx.x;              // 16*64 = 1024 blocks
    int n   = bid >> 6;
    int p4  = ((bid & 63) << 8) + threadIdx.x;   // 0..16383
    const float4* xp = x + (size_t)n * CCH * HW4 + p4;
    float4 acc = make_float4(0.f, 0.f, 0.f, 0.f);
    #pragma unroll 8
    for (int c = 0; c < CCH; ++c) {
        float4 v = xp[(size_t)c * HW4];
        acc.x += v.x; acc.y += v.y; acc.z += v.z; acc.w += v.w;
    }
    const float s = 1.0f / 64.0f;
    acc.x *= s; acc.y *= s; acc.z *= s; acc.w *= s;
    gray[(size_t)n * HW4 + p4] = acc;
}

// ---------------- Kernel 2: 7 convs + edge combine ----------------
__global__ __launch_bounds__(256) void conv_kernel(const float* __restrict__ gray,
                                                   float* __restrict__ comb) {
    __shared__ float t[TS + 6][TS + 7];   // 22 x 23 (pad col to soften bank conflicts)
    int n  = blockIdx.z;
    int h0 = blockIdx.y * TS - 3;
    int w0 = blockIdx.x * TS - 3;
    const float* g = gray + (size_t)n * HW;

    int tid = threadIdx.y * TS + threadIdx.x;
    for (int i = tid; i < 22 * 22; i += 256) {
        int r  = i / 22, c2 = i - r * 22;
        int hh = h0 + r, ww = w0 + c2;
        t[r][c2] = (hh >= 0 && hh < H && ww >= 0 && ww < W) ? g[hh * W + ww] : 0.f;
    }
    __syncthreads();

    int ty = threadIdx.y, tx = threadIdx.x;
    float v[7][7];
    #pragma unroll
    for (int i = 0; i < 7; ++i)
        #pragma unroll
        for (int j = 0; j < 7; ++j)
            v[i][j] = t[ty + i][tx + j];

    // Separable Sobel evaluations (cross-correlation; antisymmetric kernels are
    // sign-invariant under flip after squaring).
    float gx7 = 0.f, gy7 = 0.f;
    {
        const float vw[7] = {1.f, 6.f, 15.f, 20.f, 15.f, 6.f, 1.f};
        const float dw[7] = {-1.f, -4.f, -5.f, 0.f, 5.f, 4.f, 1.f};
        #pragma unroll
        for (int i = 0; i < 7; ++i) {
            float rh = -v[i][0] - 4.f*v[i][1] - 5.f*v[i][2] + 5.f*v[i][4] + 4.f*v[i][5] + v[i][6];
            float rs =  v[i][0] + 6.f*v[i][1] + 15.f*v[i][2] + 20.f*v[i][3] + 15.f*v[i][4] + 6.f*v[i][5] + v[i][6];
            gx7 += vw[i] * rh;
            gy7 += dw[i] * rs;
        }
    }
    float gx5 = 0.f, gy5 = 0.f;
    {
        const float vw[5] = {1.f, 4.f, 6.f, 4.f, 1.f};
        const float dw[5] = {-1.f, -2.f, 0.f, 2.f, 1.f};
        #pragma unroll
        for (int i = 0; i < 5; ++i) {
            float rh = -v[i+1][1] - 2.f*v[i+1][2] + 2.f*v[i+1][4] + v[i+1][5];
            float rs =  v[i+1][1] + 4.f*v[i+1][2] + 6.f*v[i+1][3] + 4.f*v[i+1][4] + v[i+1][5];
            gx5 += vw[i] * rh;
            gy5 += dw[i] * rs;
        }
    }
    float gx3 = 0.f, gy3 = 0.f;
    {
        const float vw[3] = {1.f, 2.f, 1.f};
        const float dw[3] = {-1.f, 0.f, 1.f};
        #pragma unroll
        for (int i = 0; i < 3; ++i) {
            float rh = v[i+2][4] - v[i+2][2];
            float rs = v[i+2][2] + 2.f*v[i+2][3] + v[i+2][4];
            gx3 += vw[i] * rh;
            gy3 += dw[i] * rs;
        }
    }
    float lap = v[2][3] + v[4][3] + v[3][2] + v[3][4] - 4.f*v[3][3];

    float e3 = sqrtf(gx3*gx3 + gy3*gy3 + 1e-6f);
    float e5 = sqrtf(gx5*gx5 + gy5*gy5 + 1e-6f);
    float e7 = sqrtf(gx7*gx7 + gy7*gy7 + 1e-6f);
    float combined = (e3 + e5 + e7 + fabsf(lap)) * 0.25f;

    comb[(size_t)n * HW + (size_t)(h0 + 3 + ty) * W + (w0 + 3 + tx)] = combined;
}

// ---------------- Kernel 3: per-image mean / std (ddof=1) ----------------
__global__ __launch_bounds__(1024) void stats_kernel(const float* __restrict__ comb,
                                                     float* __restrict__ stats) {
    __shared__ float ssum[1024];
    __shared__ float ssq[1024];
    int n = blockIdx.x;
    const float* c = comb + (size_t)n * HW;
    float s = 0.f, q = 0.f;
    for (int i = threadIdx.x; i < HW; i += 1024) {
        float v = c[i];
        s += v;
        q += v * v;
    }
    ssum[threadIdx.x] = s;
    ssq[threadIdx.x]  = q;
    __syncthreads();
    for (int off = 512; off > 0; off >>= 1) {
        if ((int)threadIdx.x < off) {
            ssum[threadIdx.x] += ssum[threadIdx.x + off];
            ssq[threadIdx.x]  += ssq[threadIdx.x + off];
        }
        __syncthreads();
    }
    if (threadIdx.x == 0) {
        float mu  = ssum[0] / (float)HW;
        float var = (ssq[0] - (float)HW * mu * mu) / (float)(HW - 1);
        var = fmaxf(var, 0.f);
        float sigma = sqrtf(var) + 1e-6f;
        stats[2 * n]     = mu;
        stats[2 * n + 1] = 1.0f / sigma;
    }
}

// ---------------- Kernel 4: factor map = 1 + sigmoid(g*norm + b) ----------------
__global__ __launch_bounds__(256) void fmap_kernel(const float* __restrict__ comb,
                                                   const float* __restrict__ stats,
                                                   float* __restrict__ fmap) {
    int idx = blockIdx.x * 256 + threadIdx.x;      // 16*65536 / 256 = 4096 blocks
    int n   = idx >> 16;
    float mu  = stats[2 * n];
    float inv = stats[2 * n + 1];
    float cmb = comb[idx];
    float z = 5.0f * (cmb - mu) * inv - 2.5f;
    float b = 1.0f / (1.0f + __expf(-z));
    fmap[idx] = 1.0f + b;
}

// ---------------- Kernel 5: out = x * fmap ----------------
__global__ __launch_bounds__(256) void mul_kernel(const float4* __restrict__ x,
                                                  const float4* __restrict__ fmap4,
                                                  float4* __restrict__ out) {
    const size_t total = (size_t)N_IMG * CCH * HW4;    // 16,777,216 float4
    size_t stride = (size_t)gridDim.x * 256;
    for (size_t i = (size_t)blockIdx.x * 256 + threadIdx.x; i < total; i += stride) {
        int p4 = (int)(i & (HW4 - 1));     // pixel / 4 within image
        int n  = (int)(i >> 20);           // 64 ch * 16384 float4 = 2^20 per image
        float4 f = fmap4[((size_t)n << 14) + p4];
        float4 v = x[i];
        v.x *= f.x; v.y *= f.y; v.z *= f.z; v.w *= f.w;
        out[i] = v;
    }
}

extern "C" void kernel_launch(void* const* d_in, const int* in_sizes, int n_in,
                              void* d_out, int out_size, void* d_ws, size_t ws_size,
                              hipStream_t stream) {
    const float* x = (const float*)d_in[0];
    float* out = (float*)d_out;
    char* ws = (char*)d_ws;

    float* gray  = (float*)ws;                                   // 4 MiB
    float* comb  = (float*)(ws + (size_t)N_IMG * HW * 4);        // 4 MiB
    float* stats = (float*)(ws + (size_t)2 * N_IMG * HW * 4);    // 128 B
    float* fmap  = gray;   // gray is dead after conv_kernel; reuse

    gray_kernel<<<N_IMG * 64, 256, 0, stream>>>((const float4*)x, (float4*)gray);

    dim3 cgrid(W / TS, H / TS, N_IMG);
    conv_kernel<<<cgrid, dim3(TS, TS), 0, stream>>>(gray, comb);

    stats_kernel<<<N_IMG, 1024, 0, stream>>>(comb, stats);

    fmap_kernel<<<(N_IMG * HW) / 256, 256, 0, stream>>>(comb, stats, fmap);

    mul_kernel<<<2048, 256, 0, stream>>>((const float4*)x, (const float4*)fmap, (float4*)out);
}

// Round 3
// 165.417 us; speedup vs baseline: 1.2209x; 1.2209x over previous
//
#include <hip/hip_runtime.h>
#include <math.h>

#define N_IMG 16
#define CCH   64
#define H     256
#define W     256
#define HW    (H*W)      // 65536
#define HW4   (HW/4)     // 16384
#define TS    16

typedef float fx4 __attribute__((ext_vector_type(4)));

// ---------------- Kernel 1: gray = mean over channels ----------------
__global__ __launch_bounds__(256) void gray_kernel(const float4* __restrict__ x,
                                                   float4* __restrict__ gray) {
    int bid = blockIdx.x;              // 16*64 = 1024 blocks
    int n   = bid >> 6;
    int p4  = ((bid & 63) << 8) + threadIdx.x;   // 0..16383
    const float4* xp = x + (size_t)n * CCH * HW4 + p4;
    float4 acc = make_float4(0.f, 0.f, 0.f, 0.f);
    #pragma unroll 8
    for (int c = 0; c < CCH; ++c) {
        float4 v = xp[(size_t)c * HW4];
        acc.x += v.x; acc.y += v.y; acc.z += v.z; acc.w += v.w;
    }
    const float s = 1.0f / 64.0f;
    acc.x *= s; acc.y *= s; acc.z *= s; acc.w *= s;
    gray[(size_t)n * HW4 + p4] = acc;
}

// ---------------- Kernel 2: 7 convs + edge combine + per-block stats partials ----------------
__global__ __launch_bounds__(256) void conv_kernel(const float* __restrict__ gray,
                                                   float* __restrict__ comb,
                                                   float2* __restrict__ part) {
    __shared__ float t[TS + 6][TS + 7];   // 22 x 23
    __shared__ float rs[256];
    __shared__ float rq[256];
    int n  = blockIdx.z;
    int h0 = blockIdx.y * TS - 3;
    int w0 = blockIdx.x * TS - 3;
    const float* g = gray + (size_t)n * HW;

    int tid = threadIdx.y * TS + threadIdx.x;
    for (int i = tid; i < 22 * 22; i += 256) {
        int r  = i / 22, c2 = i - r * 22;
        int hh = h0 + r, ww = w0 + c2;
        t[r][c2] = (hh >= 0 && hh < H && ww >= 0 && ww < W) ? g[hh * W + ww] : 0.f;
    }
    __syncthreads();

    int ty = threadIdx.y, tx = threadIdx.x;
    float v[7][7];
    #pragma unroll
    for (int i = 0; i < 7; ++i)
        #pragma unroll
        for (int j = 0; j < 7; ++j)
            v[i][j] = t[ty + i][tx + j];

    float gx7 = 0.f, gy7 = 0.f;
    {
        const float vw[7] = {1.f, 6.f, 15.f, 20.f, 15.f, 6.f, 1.f};
        const float dw[7] = {-1.f, -4.f, -5.f, 0.f, 5.f, 4.f, 1.f};
        #pragma unroll
        for (int i = 0; i < 7; ++i) {
            float rh = -v[i][0] - 4.f*v[i][1] - 5.f*v[i][2] + 5.f*v[i][4] + 4.f*v[i][5] + v[i][6];
            float rsu =  v[i][0] + 6.f*v[i][1] + 15.f*v[i][2] + 20.f*v[i][3] + 15.f*v[i][4] + 6.f*v[i][5] + v[i][6];
            gx7 += vw[i] * rh;
            gy7 += dw[i] * rsu;
        }
    }
    float gx5 = 0.f, gy5 = 0.f;
    {
        const float vw[5] = {1.f, 4.f, 6.f, 4.f, 1.f};
        const float dw[5] = {-1.f, -2.f, 0.f, 2.f, 1.f};
        #pragma unroll
        for (int i = 0; i < 5; ++i) {
            float rh = -v[i+1][1] - 2.f*v[i+1][2] + 2.f*v[i+1][4] + v[i+1][5];
            float rsu =  v[i+1][1] + 4.f*v[i+1][2] + 6.f*v[i+1][3] + 4.f*v[i+1][4] + v[i+1][5];
            gx5 += vw[i] * rh;
            gy5 += dw[i] * rsu;
        }
    }
    float gx3 = 0.f, gy3 = 0.f;
    {
        const float vw[3] = {1.f, 2.f, 1.f};
        const float dw[3] = {-1.f, 0.f, 1.f};
        #pragma unroll
        for (int i = 0; i < 3; ++i) {
            float rh = v[i+2][4] - v[i+2][2];
            float rsu = v[i+2][2] + 2.f*v[i+2][3] + v[i+2][4];
            gx3 += vw[i] * rh;
            gy3 += dw[i] * rsu;
        }
    }
    float lap = v[2][3] + v[4][3] + v[3][2] + v[3][4] - 4.f*v[3][3];

    float e3 = sqrtf(gx3*gx3 + gy3*gy3 + 1e-6f);
    float e5 = sqrtf(gx5*gx5 + gy5*gy5 + 1e-6f);
    float e7 = sqrtf(gx7*gx7 + gy7*gy7 + 1e-6f);
    float combined = (e3 + e5 + e7 + fabsf(lap)) * 0.25f;

    comb[(size_t)n * HW + (size_t)(h0 + 3 + ty) * W + (w0 + 3 + tx)] = combined;

    // block-level sum / sumsq partials (deterministic tree reduce)
    rs[tid] = combined;
    rq[tid] = combined * combined;
    __syncthreads();
    for (int off = 128; off > 0; off >>= 1) {
        if (tid < off) {
            rs[tid] += rs[tid + off];
            rq[tid] += rq[tid + off];
        }
        __syncthreads();
    }
    if (tid == 0) {
        int blockLin = blockIdx.y * (W / TS) + blockIdx.x;   // 0..255
        part[n * 256 + blockLin] = make_float2(rs[0], rq[0]);
    }
}

// ---------------- Kernel 3: finalize per-image mean / inv-std (ddof=1) ----------------
__global__ __launch_bounds__(256) void stats_kernel(const float2* __restrict__ part,
                                                    float2* __restrict__ stats) {
    __shared__ float ssum[256];
    __shared__ float ssq[256];
    int n = blockIdx.x;
    float2 p = part[n * 256 + threadIdx.x];
    ssum[threadIdx.x] = p.x;
    ssq[threadIdx.x]  = p.y;
    __syncthreads();
    for (int off = 128; off > 0; off >>= 1) {
        if ((int)threadIdx.x < off) {
            ssum[threadIdx.x] += ssum[threadIdx.x + off];
            ssq[threadIdx.x]  += ssq[threadIdx.x + off];
        }
        __syncthreads();
    }
    if (threadIdx.x == 0) {
        float mu  = ssum[0] / (float)HW;
        float var = (ssq[0] - (float)HW * mu * mu) / (float)(HW - 1);
        var = fmaxf(var, 0.f);
        float sigma = sqrtf(var) + 1e-6f;
        stats[n] = make_float2(mu, 1.0f / sigma);
    }
}

// ---------------- Kernel 4: out = x * (1 + sigmoid(g*norm + b)), fused ----------------
__global__ __launch_bounds__(256) void mul_kernel(const float4* __restrict__ x,
                                                  const float4* __restrict__ comb4,
                                                  const float2* __restrict__ stats,
                                                  fx4* __restrict__ out) {
    const size_t total = (size_t)N_IMG * CCH * HW4;    // 16,777,216 float4
    size_t stride = (size_t)gridDim.x * 256;
    for (size_t i = (size_t)blockIdx.x * 256 + threadIdx.x; i < total; i += stride) {
        int p4 = (int)(i & (HW4 - 1));     // pixel/4 within image
        int n  = (int)(i >> 20);           // 2^20 float4 per image
        float2 st = stats[n];
        float4 c = comb4[((size_t)n << 14) + p4];
        float4 v = x[i];
        fx4 r;
        r.x = v.x * (1.0f + 1.0f / (1.0f + __expf(2.5f - 5.0f * (c.x - st.x) * st.y)));
        r.y = v.y * (1.0f + 1.0f / (1.0f + __expf(2.5f - 5.0f * (c.y - st.x) * st.y)));
        r.z = v.z * (1.0f + 1.0f / (1.0f + __expf(2.5f - 5.0f * (c.z - st.x) * st.y)));
        r.w = v.w * (1.0f + 1.0f / (1.0f + __expf(2.5f - 5.0f * (c.w - st.x) * st.y)));
        __builtin_nontemporal_store(r, &out[i]);
    }
}

extern "C" void kernel_launch(void* const* d_in, const int* in_sizes, int n_in,
                              void* d_out, int out_size, void* d_ws, size_t ws_size,
                              hipStream_t stream) {
    const float* x = (const float*)d_in[0];
    float* out = (float*)d_out;
    char* ws = (char*)d_ws;

    float*  gray  = (float*)ws;                                    // 4 MiB
    float*  comb  = (float*)(ws + (size_t)N_IMG * HW * 4);         // 4 MiB
    float2* part  = (float2*)(ws + (size_t)2 * N_IMG * HW * 4);    // 32 KiB
    float2* stats = (float2*)(ws + (size_t)2 * N_IMG * HW * 4 + 4096 * sizeof(float2));

    gray_kernel<<<N_IMG * 64, 256, 0, stream>>>((const float4*)x, (float4*)gray);

    dim3 cgrid(W / TS, H / TS, N_IMG);
    conv_kernel<<<cgrid, dim3(TS, TS), 0, stream>>>(gray, comb, part);

    stats_kernel<<<N_IMG, 256, 0, stream>>>(part, stats);

    mul_kernel<<<2048, 256, 0, stream>>>((const float4*)x, (const float4*)comb,
                                         stats, (fx4*)out);
}